// Round 6
// baseline (198.727 us; speedup 1.0000x reference)
//
#include <hip/hip_runtime.h>
#include <hip/hip_bf16.h>
#include <math.h>

#define B_ 2
#define T_ 2048
#define C_ 1024
#define H_ 16
#define HKV_ 4
#define G_ 4
#define HD_ 64
#define KVC_ 256      // HKV*HD
#define NQKV_ 1536    // C_ + 2*KVC_
#define NQT_ 32       // T_/64 q-tiles

typedef __attribute__((ext_vector_type(8))) short bf16x8;
typedef __attribute__((ext_vector_type(4))) float f32x4;

static __device__ inline short f2bf(float f) {          // RNE (off hot path)
    __hip_bfloat16 h = __float2bfloat16(f);
    short s;
    __builtin_memcpy(&s, &h, 2);
    return s;
}
static __device__ inline short f2bf_trunc(float f) {    // RTZ, 1 op (hot path)
    unsigned int u;
    __builtin_memcpy(&u, &f, 4);
    return (short)(u >> 16);
}
static __device__ inline float bf2f(short s) {
    unsigned int u = ((unsigned int)(unsigned short)s) << 16;
    float f;
    __builtin_memcpy(&f, &u, 4);
    return f;
}

// async global->LDS, 16B per lane; lds base wave-uniform, dest = base + lane*16.
static __device__ inline void gload_lds16(const short* g, short* lds) {
    __builtin_amdgcn_global_load_lds(
        (const __attribute__((address_space(1))) unsigned int*)g,
        (__attribute__((address_space(3))) unsigned int*)lds, 16, 0, 0);
}

// ---------------- elementwise fp32 -> bf16 cast (8 elems/thread) ----------
__global__ __launch_bounds__(256) void cast_bf16(
    const float* __restrict__ in, short* __restrict__ out, int n)
{
    const int i = (blockIdx.x * 256 + threadIdx.x) * 8;
    if (i >= n) return;
    const float4 a = *(const float4*)(in + i);
    const float4 b = *(const float4*)(in + i + 4);
    bf16x8 o;
    o[0] = f2bf(a.x); o[1] = f2bf(a.y); o[2] = f2bf(a.z); o[3] = f2bf(a.w);
    o[4] = f2bf(b.x); o[5] = f2bf(b.y); o[6] = f2bf(b.z); o[7] = f2bf(b.w);
    *(bf16x8*)(out + i) = o;
}

// ------------- fused weight transpose+cast (z selects matrix) -------------
__global__ __launch_bounds__(256) void w_transpose(
    const float* __restrict__ Wq, const float* __restrict__ Wk,
    const float* __restrict__ Wv, const float* __restrict__ Wo,
    short* __restrict__ Wt, short* __restrict__ Wot)
{
    const int z = blockIdx.z;
    const float* in;
    short* out;
    int N;
    if (z == 0)      { in = Wq; out = Wt;                     N = C_; }
    else if (z == 1) { in = Wk; out = Wt + C_ * C_;           N = KVC_; }
    else if (z == 2) { in = Wv; out = Wt + (C_ + KVC_) * C_;  N = KVC_; }
    else             { in = Wo; out = Wot;                    N = C_; }
    const int n0 = blockIdx.x * 32;
    if (n0 >= N) return;
    __shared__ float t[32][33];
    const int tx = threadIdx.x, ty = threadIdx.y;     // 32 x 8
    const int k0 = blockIdx.y * 32;
    #pragma unroll
    for (int j = 0; j < 4; j++)
        t[ty + j * 8][tx] = in[(size_t)(k0 + ty + j * 8) * N + n0 + tx];
    __syncthreads();
    #pragma unroll
    for (int j = 0; j < 4; j++)
        out[(size_t)(n0 + ty + j * 8) * C_ + k0 + tx] = f2bf(t[tx][ty + j * 8]);
}

// ---------------- bf16 MFMA GEMM: 128x128 tile, BK=32, double-buffered ----
template <bool OUT_BF16>
__global__ __launch_bounds__(256) void gemm_bf16(
    const short* __restrict__ A, const short* __restrict__ Bt,
    void* __restrict__ Cout, int M, int N, int K)
{
    __shared__ short As[2][128 * 32];
    __shared__ short Bs[2][128 * 32];
    const int tid = threadIdx.x;
    const int wave = tid >> 6, lane = tid & 63;
    const int l15 = lane & 15, quad = lane >> 4;
    const int row0 = blockIdx.y * 128, col0 = blockIdx.x * 128;
    const int wr = (wave >> 1) * 64, wc = (wave & 1) * 64;
    const int sr = lane >> 2, kof = (lane & 3) * 8;

    f32x4 acc[4][4];
    #pragma unroll
    for (int i = 0; i < 4; i++)
        #pragma unroll
        for (int j = 0; j < 4; j++)
            acc[i][j] = (f32x4){0.f, 0.f, 0.f, 0.f};

#define GSTAGE(KT, BUF) do {                                                   \
        _Pragma("unroll")                                                      \
        for (int i_ = 0; i_ < 2; i_++) {                                       \
            const int rr = i_ * 64 + wave * 16;                                \
            gload_lds16(A + (size_t)(row0 + rr + sr) * K + (KT) + kof,         \
                        &As[BUF][rr * 32]);                                    \
            gload_lds16(Bt + (size_t)(col0 + rr + sr) * K + (KT) + kof,        \
                        &Bs[BUF][rr * 32]);                                    \
        }                                                                      \
    } while (0)

    GSTAGE(0, 0);
    asm volatile("s_waitcnt vmcnt(0)" ::: "memory");
    __builtin_amdgcn_s_barrier();

    int cur = 0;
    const int nkt = K >> 5;
    for (int t = 0; t < nkt; ++t) {
        if (t + 1 < nkt) GSTAGE((t + 1) * 32, cur ^ 1);

        bf16x8 af[4], bfr[4];
        #pragma unroll
        for (int mt = 0; mt < 4; mt++)
            af[mt] = *(const bf16x8*)&As[cur][(wr + mt * 16 + l15) * 32 + quad * 8];
        #pragma unroll
        for (int nt = 0; nt < 4; nt++)
            bfr[nt] = *(const bf16x8*)&Bs[cur][(wc + nt * 16 + l15) * 32 + quad * 8];
        #pragma unroll
        for (int mt = 0; mt < 4; mt++)
            #pragma unroll
            for (int nt = 0; nt < 4; nt++)
                acc[mt][nt] = __builtin_amdgcn_mfma_f32_16x16x32_bf16(
                    af[mt], bfr[nt], acc[mt][nt], 0, 0, 0);

        asm volatile("s_waitcnt vmcnt(0)" ::: "memory");
        __builtin_amdgcn_s_barrier();
        cur ^= 1;
    }
#undef GSTAGE

    #pragma unroll
    for (int mt = 0; mt < 4; mt++) {
        #pragma unroll
        for (int r = 0; r < 4; r++) {
            const size_t row = row0 + wr + mt * 16 + quad * 4 + r;
            #pragma unroll
            for (int nt = 0; nt < 4; nt++) {
                const size_t col = col0 + wc + nt * 16 + l15;
                if (OUT_BF16)
                    ((short*)Cout)[row * N + col] = f2bf(acc[mt][nt][r]);
                else
                    ((float*)Cout)[row * N + col] = acc[mt][nt][r];
            }
        }
    }
}

// ---------------- K/V tiling prepass: MFMA fragment-stream layout ---------
// Per (bk, jt) 4096-short tile, chunk i (0..7) of 512 shorts, lane = quad*16+l15:
//  K-tile chunk i=nt*2+k0, lane, j :  K[nt*16 + l15][(k0*4+quad)*8 + j]
//  V-tile chunk i=nt*2+k0, lane, j :  V^T[nt*16 + l15][k0*32 + quad*8 + j]
// so attn's kf[i]/vf[i] = one coalesced 16B/lane global load, no LDS.
__global__ __launch_bounds__(256) void kv_tile(
    const short* __restrict__ QKV, short* __restrict__ Kt, short* __restrict__ Vt)
{
    __shared__ short Ls[64 * 72];
    const int jt = blockIdx.x;         // 0..31
    const int bk = blockIdx.y;         // 0..7 = b*4+kh
    const int b = bk >> 2, kh = bk & 3;
    const int tid = threadIdx.x;
    const int key = tid >> 2, d16 = (tid & 3) * 16;
    const size_t src = (size_t)(b * T_ + jt * 64 + key) * NQKV_ + C_ + kh * 64 + d16;
    const size_t tbase = (size_t)(bk * 32 + jt) * 4096;

    {   // K: thread holds K[key][d16..d16+15] -> stream position
        const int i = (key >> 4) * 2 + (d16 >> 5);
        const int qd = (d16 & 31) >> 3;           // quad of first 8: 0 or 2
        short* dst = Kt + tbase + i * 512 + (qd * 16 + (key & 15)) * 8;
        *(bf16x8*)dst         = *(const bf16x8*)(QKV + src);      // d16..+7
        *(bf16x8*)(dst + 128) = *(const bf16x8*)(QKV + src + 8);  // d16+8..+15
    }
    // V: transpose through LDS, then stream-store
    *(bf16x8*)&Ls[key * 72 + d16]     = *(const bf16x8*)(QKV + src + KVC_);
    *(bf16x8*)&Ls[key * 72 + d16 + 8] = *(const bf16x8*)(QKV + src + KVC_ + 8);
    __syncthreads();
    const int d = tid >> 2, k16 = (tid & 3) * 16;
    bf16x8 o0, o1;
    #pragma unroll
    for (int i = 0; i < 8; i++) o0[i] = Ls[(k16 + i) * 72 + d];      // V^T[d][k16..+7]
    #pragma unroll
    for (int i = 0; i < 8; i++) o1[i] = Ls[(k16 + 8 + i) * 72 + d];  // V^T[d][k16+8..+15]
    {
        const int i = (d >> 4) * 2 + (k16 >> 5);
        const int qk = (k16 & 31) >> 3;           // 0 or 2
        short* dst = Vt + tbase + i * 512 + (qk * 16 + (d & 15)) * 8;
        *(bf16x8*)dst         = o0;
        *(bf16x8*)(dst + 128) = o1;
    }
}

// ---------------- MFMA flash attention, dynamic load balance --------------
// v6: ONE q-tile per block (grid 32x32 = 1024 blocks), longest tile first
// (qt = 31 - blockIdx.x) so the CP backfills short blocks -> ~4 blocks/CU
// = 4 waves/SIMD of TLP (vs 2 with the static H/L pairing), hiding the
// serial QK->softmax->P->PV chain. K/V fragments global->VGPR from the
// fragment-stream tiles (L2-resident) with 1-tile register prefetch; no
// barriers in the main loop. exp2-domain fixed-shift softmax; ones-MFMA
// row sums; causal mask on the diagonal iteration only.
#define LSTR 72

__global__ __launch_bounds__(256, 4) void attn_mfma(
    const short* __restrict__ QKV, const short* __restrict__ Ktg,
    const short* __restrict__ Vtg, short* __restrict__ Y)
{
    const int qt = NQT_ - 1 - blockIdx.x;      // longest-first dispatch
    const int bh = blockIdx.y;
    const int b = bh >> 4, h = bh & 15, kh = h >> 2;
    const float slope2 = exp2f(-0.5f * (float)(kh + 1)) * 1.44269504f;
    const int tid = threadIdx.x;
    const int wave = tid >> 6, lane = tid & 63;
    const int l15 = lane & 15, quad = lane >> 4;

    __shared__ short Ps[4 * 16 * LSTR];        // per wave: 16 q-rows
    short* Pw = &Ps[wave * 16 * LSTR];
    const int wswz = ((quad >> 1) & 1) << 4;   // P write XOR (row bit3)
    const int rswz = ((l15 >> 3) & 1) << 4;    // P read  XOR (row bit3)

    const size_t bT = (size_t)b * T_;
    const size_t tb0 = (size_t)((b * HKV_ + kh) * 32) * 4096;
    const short* Kt = Ktg + tb0;
    const short* Vt = Vtg + tb0;
    const int qrow0 = qt * 64 + wave * 16;

    // Q fragments; scale 1/8 * 1/ln2 folded in (exp2-domain scores)
    const float qscale = 0.125f * 1.44269504f;
    bf16x8 qf[2];
    #pragma unroll
    for (int k0 = 0; k0 < 2; k0++) {
        const short* qp = QKV + (bT + qrow0 + l15) * NQKV_ + h * 64;
        bf16x8 r = *(const bf16x8*)(qp + k0 * 32 + quad * 8);
        #pragma unroll
        for (int j = 0; j < 8; j++)
            qf[k0][j] = f2bf(bf2f(r[j]) * qscale);
    }

    const short one_s = (short)0x3F80;         // bf16 1.0
    const bf16x8 ones = {one_s, one_s, one_s, one_s, one_s, one_s, one_s, one_s};

    f32x4 Oacc[4], lacc;
    #pragma unroll
    for (int nt = 0; nt < 4; nt++)
        Oacc[nt] = (f32x4){0.f, 0.f, 0.f, 0.f};
    lacc = (f32x4){0.f, 0.f, 0.f, 0.f};

    // prologue: fragment loads for tile 0 (global -> VGPR, coalesced)
    bf16x8 kf[8], vf[8];
    #pragma unroll
    for (int i = 0; i < 8; i++)
        kf[i] = *(const bf16x8*)(Kt + i * 512 + lane * 8);
    #pragma unroll
    for (int i = 0; i < 8; i++)
        vf[i] = *(const bf16x8*)(Vt + i * 512 + lane * 8);

    for (int jtk = 0; jtk <= qt; jtk++) {
        const int pjt = (jtk < qt) ? jtk + 1 : qt;     // clamped prefetch tile

        // S = (Q * qscale) K^T
        f32x4 s[4];
        #pragma unroll
        for (int nt = 0; nt < 4; nt++) {
            f32x4 a = {0.f, 0.f, 0.f, 0.f};
            a = __builtin_amdgcn_mfma_f32_16x16x32_bf16(qf[0], kf[nt*2+0], a, 0, 0, 0);
            a = __builtin_amdgcn_mfma_f32_16x16x32_bf16(qf[1], kf[nt*2+1], a, 0, 0, 0);
            s[nt] = a;
        }

        // prefetch next K fragments (kf consumed above; ~full iter to cover L2)
        #pragma unroll
        for (int i = 0; i < 8; i++)
            kf[i] = *(const bf16x8*)(Kt + (size_t)pjt * 4096 + i * 512 + lane * 8);

        // exp2-domain softmax + ALiBi; mask only on diagonal tile (uniform)
        {
            const float base = slope2 * (float)(jtk * 64 + l15 - quad * 4 - qrow0);
            if (jtk == qt) {    // diagonal: apply causal mask
                #pragma unroll
                for (int nt = 0; nt < 4; nt++) {
                    const int colsw = ((nt * 16 + l15) ^ wswz);
                    #pragma unroll
                    for (int r = 0; r < 4; r++) {
                        const float relv = (float)(jtk * 64 + l15 - quad * 4 - qrow0)
                                         + (float)(nt * 16 - r);
                        float p = __builtin_amdgcn_exp2f(
                            fmaf(slope2, (float)(nt * 16 - r), base) + s[nt][r]);
                        if (relv > 0.f) p = 0.f;
                        Pw[(quad * 4 + r) * LSTR + colsw] = f2bf_trunc(p);
                    }
                }
            } else {            // clean path: add + exp + shr + write
                #pragma unroll
                for (int nt = 0; nt < 4; nt++) {
                    const int colsw = ((nt * 16 + l15) ^ wswz);
                    #pragma unroll
                    for (int r = 0; r < 4; r++) {
                        float p = __builtin_amdgcn_exp2f(
                            fmaf(slope2, (float)(nt * 16 - r), base) + s[nt][r]);
                        Pw[(quad * 4 + r) * LSTR + colsw] = f2bf_trunc(p);
                    }
                }
            }
        }
        __asm__ volatile("s_waitcnt lgkmcnt(0)" ::: "memory");

        // O += P @ V, l += P @ 1 (ones-MFMA row sums)
        {
            bf16x8 pf0 = *(const bf16x8*)&Pw[l15 * LSTR + ((quad * 8) ^ rswz)];
            bf16x8 pf1 = *(const bf16x8*)&Pw[l15 * LSTR + ((32 + quad * 8) ^ rswz)];
            lacc = __builtin_amdgcn_mfma_f32_16x16x32_bf16(pf0, ones, lacc, 0, 0, 0);
            lacc = __builtin_amdgcn_mfma_f32_16x16x32_bf16(pf1, ones, lacc, 0, 0, 0);
            #pragma unroll
            for (int nt = 0; nt < 4; nt++) {
                Oacc[nt] = __builtin_amdgcn_mfma_f32_16x16x32_bf16(
                    pf0, vf[nt*2+0], Oacc[nt], 0, 0, 0);
                Oacc[nt] = __builtin_amdgcn_mfma_f32_16x16x32_bf16(
                    pf1, vf[nt*2+1], Oacc[nt], 0, 0, 0);
            }
        }

        // prefetch next V fragments (vf consumed above)
        #pragma unroll
        for (int i = 0; i < 8; i++)
            vf[i] = *(const bf16x8*)(Vt + (size_t)pjt * 4096 + i * 512 + lane * 8);
    }

    // epilogue: l = lacc[r] (same in all 16 col-lanes), normalize, store bf16
    #pragma unroll
    for (int r = 0; r < 4; r++) {
        const float inv = 1.f / lacc[r];
        const int row = qrow0 + quad * 4 + r;
        short* yp = Y + (bT + row) * C_ + h * 64 + l15;
        #pragma unroll
        for (int nt = 0; nt < 4; nt++)
            yp[nt * 16] = f2bf(Oacc[nt][r] * inv);
    }
}

extern "C" void kernel_launch(void* const* d_in, const int* in_sizes, int n_in,
                              void* d_out, int out_size, void* d_ws, size_t ws_size,
                              hipStream_t stream) {
    const float* x  = (const float*)d_in[0];
    const float* Wq = (const float*)d_in[1];
    const float* Wk = (const float*)d_in[2];
    const float* Wv = (const float*)d_in[3];
    const float* Wo = (const float*)d_in[4];
    float* out = (float*)d_out;

    const int M = B_ * T_;                           // 4096
    short* xb  = (short*)d_ws;                       // [4096][1024]
    short* Wt  = xb  + (size_t)M * C_;               // [1536][1024]
    short* Wot = Wt  + (size_t)NQKV_ * C_;           // [1024][1024]
    short* QKV = Wot + (size_t)C_ * C_;              // [4096][1536]
    short* Yb  = QKV + (size_t)M * NQKV_;            // [4096][1024]
    short* Ktg = Yb  + (size_t)M * C_;               // [8][32][4096] frag-stream
    short* Vtg = Ktg + (size_t)8 * 32 * 4096;        // [8][32][4096] frag-stream

    cast_bf16<<<dim3(M * C_ / (256 * 8)), dim3(256), 0, stream>>>(x, xb, M * C_);
    w_transpose<<<dim3(32, 32, 4), dim3(32, 8), 0, stream>>>(Wq, Wk, Wv, Wo, Wt, Wot);

    gemm_bf16<true><<<dim3(NQKV_ / 128, M / 128), dim3(256), 0, stream>>>(
        xb, Wt, QKV, M, NQKV_, C_);
    kv_tile<<<dim3(32, 8), dim3(256), 0, stream>>>(QKV, Ktg, Vtg);
    attn_mfma<<<dim3(NQT_, B_ * H_), dim3(256), 0, stream>>>(QKV, Ktg, Vtg, Yb);
    gemm_bf16<false><<<dim3(C_ / 128, M / 128), dim3(256), 0, stream>>>(
        Yb, Wot, out, M, C_, C_);
}

// Round 7
// 175.061 us; speedup vs baseline: 1.1352x; 1.1352x over previous
//
#include <hip/hip_runtime.h>
#include <hip/hip_bf16.h>
#include <math.h>

#define B_ 2
#define T_ 2048
#define C_ 1024
#define H_ 16
#define HKV_ 4
#define G_ 4
#define HD_ 64
#define KVC_ 256      // HKV*HD
#define NQKV_ 1536    // C_ + 2*KVC_
#define NQT_ 32       // T_/64 q-tiles

typedef __attribute__((ext_vector_type(8))) short bf16x8;
typedef __attribute__((ext_vector_type(4))) float f32x4;

static __device__ inline short f2bf(float f) {          // RNE (off hot path)
    __hip_bfloat16 h = __float2bfloat16(f);
    short s;
    __builtin_memcpy(&s, &h, 2);
    return s;
}
static __device__ inline short f2bf_trunc(float f) {    // RTZ, 1 op (hot path)
    unsigned int u;
    __builtin_memcpy(&u, &f, 4);
    return (short)(u >> 16);
}
static __device__ inline float bf2f(short s) {
    unsigned int u = ((unsigned int)(unsigned short)s) << 16;
    float f;
    __builtin_memcpy(&f, &u, 4);
    return f;
}

// async global->LDS, 16B per lane; lds base wave-uniform, dest = base + lane*16.
static __device__ inline void gload_lds16(const short* g, short* lds) {
    __builtin_amdgcn_global_load_lds(
        (const __attribute__((address_space(1))) unsigned int*)g,
        (__attribute__((address_space(3))) unsigned int*)lds, 16, 0, 0);
}

// ---------------- elementwise fp32 -> bf16 cast (8 elems/thread) ----------
__global__ __launch_bounds__(256) void cast_bf16(
    const float* __restrict__ in, short* __restrict__ out, int n)
{
    const int i = (blockIdx.x * 256 + threadIdx.x) * 8;
    if (i >= n) return;
    const float4 a = *(const float4*)(in + i);
    const float4 b = *(const float4*)(in + i + 4);
    bf16x8 o;
    o[0] = f2bf(a.x); o[1] = f2bf(a.y); o[2] = f2bf(a.z); o[3] = f2bf(a.w);
    o[4] = f2bf(b.x); o[5] = f2bf(b.y); o[6] = f2bf(b.z); o[7] = f2bf(b.w);
    *(bf16x8*)(out + i) = o;
}

// ------------- fused weight transpose+cast (z selects matrix) -------------
__global__ __launch_bounds__(256) void w_transpose(
    const float* __restrict__ Wq, const float* __restrict__ Wk,
    const float* __restrict__ Wv, const float* __restrict__ Wo,
    short* __restrict__ Wt, short* __restrict__ Wot)
{
    const int z = blockIdx.z;
    const float* in;
    short* out;
    int N;
    if (z == 0)      { in = Wq; out = Wt;                     N = C_; }
    else if (z == 1) { in = Wk; out = Wt + C_ * C_;           N = KVC_; }
    else if (z == 2) { in = Wv; out = Wt + (C_ + KVC_) * C_;  N = KVC_; }
    else             { in = Wo; out = Wot;                    N = C_; }
    const int n0 = blockIdx.x * 32;
    if (n0 >= N) return;
    __shared__ float t[32][33];
    const int tx = threadIdx.x, ty = threadIdx.y;     // 32 x 8
    const int k0 = blockIdx.y * 32;
    #pragma unroll
    for (int j = 0; j < 4; j++)
        t[ty + j * 8][tx] = in[(size_t)(k0 + ty + j * 8) * N + n0 + tx];
    __syncthreads();
    #pragma unroll
    for (int j = 0; j < 4; j++)
        out[(size_t)(n0 + ty + j * 8) * C_ + k0 + tx] = f2bf(t[tx][ty + j * 8]);
}

// ---------------- bf16 MFMA GEMM: 128x128 tile, BK=32, double-buffered ----
template <bool OUT_BF16>
__global__ __launch_bounds__(256) void gemm_bf16(
    const short* __restrict__ A, const short* __restrict__ Bt,
    void* __restrict__ Cout, int M, int N, int K)
{
    __shared__ short As[2][128 * 32];
    __shared__ short Bs[2][128 * 32];
    const int tid = threadIdx.x;
    const int wave = tid >> 6, lane = tid & 63;
    const int l15 = lane & 15, quad = lane >> 4;
    const int row0 = blockIdx.y * 128, col0 = blockIdx.x * 128;
    const int wr = (wave >> 1) * 64, wc = (wave & 1) * 64;
    const int sr = lane >> 2, kof = (lane & 3) * 8;

    f32x4 acc[4][4];
    #pragma unroll
    for (int i = 0; i < 4; i++)
        #pragma unroll
        for (int j = 0; j < 4; j++)
            acc[i][j] = (f32x4){0.f, 0.f, 0.f, 0.f};

#define GSTAGE(KT, BUF) do {                                                   \
        _Pragma("unroll")                                                      \
        for (int i_ = 0; i_ < 2; i_++) {                                       \
            const int rr = i_ * 64 + wave * 16;                                \
            gload_lds16(A + (size_t)(row0 + rr + sr) * K + (KT) + kof,         \
                        &As[BUF][rr * 32]);                                    \
            gload_lds16(Bt + (size_t)(col0 + rr + sr) * K + (KT) + kof,        \
                        &Bs[BUF][rr * 32]);                                    \
        }                                                                      \
    } while (0)

    GSTAGE(0, 0);
    asm volatile("s_waitcnt vmcnt(0)" ::: "memory");
    __builtin_amdgcn_s_barrier();

    int cur = 0;
    const int nkt = K >> 5;
    for (int t = 0; t < nkt; ++t) {
        if (t + 1 < nkt) GSTAGE((t + 1) * 32, cur ^ 1);

        bf16x8 af[4], bfr[4];
        #pragma unroll
        for (int mt = 0; mt < 4; mt++)
            af[mt] = *(const bf16x8*)&As[cur][(wr + mt * 16 + l15) * 32 + quad * 8];
        #pragma unroll
        for (int nt = 0; nt < 4; nt++)
            bfr[nt] = *(const bf16x8*)&Bs[cur][(wc + nt * 16 + l15) * 32 + quad * 8];
        #pragma unroll
        for (int mt = 0; mt < 4; mt++)
            #pragma unroll
            for (int nt = 0; nt < 4; nt++)
                acc[mt][nt] = __builtin_amdgcn_mfma_f32_16x16x32_bf16(
                    af[mt], bfr[nt], acc[mt][nt], 0, 0, 0);

        asm volatile("s_waitcnt vmcnt(0)" ::: "memory");
        __builtin_amdgcn_s_barrier();
        cur ^= 1;
    }
#undef GSTAGE

    #pragma unroll
    for (int mt = 0; mt < 4; mt++) {
        #pragma unroll
        for (int r = 0; r < 4; r++) {
            const size_t row = row0 + wr + mt * 16 + quad * 4 + r;
            #pragma unroll
            for (int nt = 0; nt < 4; nt++) {
                const size_t col = col0 + wc + nt * 16 + l15;
                if (OUT_BF16)
                    ((short*)Cout)[row * N + col] = f2bf(acc[mt][nt][r]);
                else
                    ((float*)Cout)[row * N + col] = acc[mt][nt][r];
            }
        }
    }
}

// ---------------- K/V tiling prepass: MFMA fragment-stream layout ---------
// Per (bk, jt) 4096-short tile, chunk i (0..7) of 512 shorts, lane = quad*16+l15:
//  K-tile chunk i=nt*2+k0, lane, j :  K[nt*16 + l15][(k0*4+quad)*8 + j]
//  V-tile chunk i=nt*2+k0, lane, j :  V^T[nt*16 + l15][k0*32 + quad*8 + j]
// so attn's kf[i]/vf[i] = one coalesced 16B/lane global load, no LDS.
__global__ __launch_bounds__(256) void kv_tile(
    const short* __restrict__ QKV, short* __restrict__ Kt, short* __restrict__ Vt)
{
    __shared__ short Ls[64 * 72];
    const int jt = blockIdx.x;         // 0..31
    const int bk = blockIdx.y;         // 0..7 = b*4+kh
    const int b = bk >> 2, kh = bk & 3;
    const int tid = threadIdx.x;
    const int key = tid >> 2, d16 = (tid & 3) * 16;
    const size_t src = (size_t)(b * T_ + jt * 64 + key) * NQKV_ + C_ + kh * 64 + d16;
    const size_t tbase = (size_t)(bk * 32 + jt) * 4096;

    {   // K: thread holds K[key][d16..d16+15] -> stream position
        const int i = (key >> 4) * 2 + (d16 >> 5);
        const int qd = (d16 & 31) >> 3;           // quad of first 8: 0 or 2
        short* dst = Kt + tbase + i * 512 + (qd * 16 + (key & 15)) * 8;
        *(bf16x8*)dst         = *(const bf16x8*)(QKV + src);      // d16..+7
        *(bf16x8*)(dst + 128) = *(const bf16x8*)(QKV + src + 8);  // d16+8..+15
    }
    // V: transpose through LDS, then stream-store
    *(bf16x8*)&Ls[key * 72 + d16]     = *(const bf16x8*)(QKV + src + KVC_);
    *(bf16x8*)&Ls[key * 72 + d16 + 8] = *(const bf16x8*)(QKV + src + KVC_ + 8);
    __syncthreads();
    const int d = tid >> 2, k16 = (tid & 3) * 16;
    bf16x8 o0, o1;
    #pragma unroll
    for (int i = 0; i < 8; i++) o0[i] = Ls[(k16 + i) * 72 + d];      // V^T[d][k16..+7]
    #pragma unroll
    for (int i = 0; i < 8; i++) o1[i] = Ls[(k16 + 8 + i) * 72 + d];  // V^T[d][k16+8..+15]
    {
        const int i = (d >> 4) * 2 + (k16 >> 5);
        const int qk = (k16 & 31) >> 3;           // 0 or 2
        short* dst = Vt + tbase + i * 512 + (qk * 16 + (d & 15)) * 8;
        *(bf16x8*)dst         = o0;
        *(bf16x8*)(dst + 128) = o1;
    }
}

// ---------------- MFMA flash attention, GQA head-pair sharing -------------
// v7: block = (q-tile, b, kh, head-pair). TWO query heads of the SAME kv
// group share every kf/vf register load -> 16KB loads fund 2 tile-comps
// EVERY iteration (round-5 averaged 1.35), total block-iters 12544->8448,
// same register/LDS footprint as round 5 (dual state = dual heads instead
// of dual q-tiles). Both heads share mask/bias indices (same q-tile) -> no
// divergent L-path. Longest-first dispatch (qt = 31-bx) for CP backfill.
// K/V fragments global->VGPR (L2-resident) with 1-tile register prefetch;
// no barriers in the main loop. exp2-domain fixed-shift softmax; ones-MFMA
// row sums; causal mask on the diagonal iteration only.
#define LSTR 72

__global__ __launch_bounds__(256) void attn_mfma(
    const short* __restrict__ QKV, const short* __restrict__ Ktg,
    const short* __restrict__ Vtg, short* __restrict__ Y)
{
    const int qt = NQT_ - 1 - blockIdx.x;      // longest-first dispatch
    const int byp = blockIdx.y;                // b(1) kh(2) hp(1)
    const int b = byp >> 3, kh = (byp >> 1) & 3, hp = byp & 1;
    const int h0 = kh * 4 + hp * 2;            // head pair h0, h0+1 (same kh)
    const float slope2 = exp2f(-0.5f * (float)(kh + 1)) * 1.44269504f;
    const int tid = threadIdx.x;
    const int wave = tid >> 6, lane = tid & 63;
    const int l15 = lane & 15, quad = lane >> 4;

    __shared__ short Ps[4 * 32 * LSTR];        // per wave: rows 0-15 h0, 16-31 h1
    short* Pw = &Ps[wave * 32 * LSTR];
    const int wswz = ((quad >> 1) & 1) << 4;   // P write XOR (row bit3)
    const int rswz = ((l15 >> 3) & 1) << 4;    // P read  XOR (row bit3)

    const size_t bT = (size_t)b * T_;
    const size_t tb0 = (size_t)((b * HKV_ + kh) * 32) * 4096;
    const short* Kt = Ktg + tb0;
    const short* Vt = Vtg + tb0;
    const int qrow0 = qt * 64 + wave * 16;

    // Q fragments for both heads; scale 1/8 * 1/ln2 folded in
    const float qscale = 0.125f * 1.44269504f;
    bf16x8 qf0[2], qf1[2];
    #pragma unroll
    for (int k0 = 0; k0 < 2; k0++) {
        const short* qp = QKV + (bT + qrow0 + l15) * NQKV_ + h0 * 64;
        bf16x8 r0 = *(const bf16x8*)(qp + k0 * 32 + quad * 8);
        bf16x8 r1 = *(const bf16x8*)(qp + 64 + k0 * 32 + quad * 8);
        #pragma unroll
        for (int j = 0; j < 8; j++) {
            qf0[k0][j] = f2bf(bf2f(r0[j]) * qscale);
            qf1[k0][j] = f2bf(bf2f(r1[j]) * qscale);
        }
    }

    const short one_s = (short)0x3F80;         // bf16 1.0
    const bf16x8 ones = {one_s, one_s, one_s, one_s, one_s, one_s, one_s, one_s};

    f32x4 Oacc0[4], Oacc1[4], lacc0, lacc1;
    #pragma unroll
    for (int nt = 0; nt < 4; nt++) {
        Oacc0[nt] = (f32x4){0.f, 0.f, 0.f, 0.f};
        Oacc1[nt] = (f32x4){0.f, 0.f, 0.f, 0.f};
    }
    lacc0 = (f32x4){0.f, 0.f, 0.f, 0.f};
    lacc1 = (f32x4){0.f, 0.f, 0.f, 0.f};

    // prologue: fragment loads for tile 0 (global -> VGPR, coalesced)
    bf16x8 kf[8], vf[8];
    #pragma unroll
    for (int i = 0; i < 8; i++)
        kf[i] = *(const bf16x8*)(Kt + i * 512 + lane * 8);
    #pragma unroll
    for (int i = 0; i < 8; i++)
        vf[i] = *(const bf16x8*)(Vt + i * 512 + lane * 8);

    for (int jtk = 0; jtk <= qt; jtk++) {
        const int pjt = (jtk < qt) ? jtk + 1 : qt;     // clamped prefetch tile

        // S = (Q * qscale) K^T for both heads (shared kf)
        f32x4 s0[4], s1[4];
        #pragma unroll
        for (int nt = 0; nt < 4; nt++) {
            f32x4 a = {0.f, 0.f, 0.f, 0.f};
            a = __builtin_amdgcn_mfma_f32_16x16x32_bf16(qf0[0], kf[nt*2+0], a, 0, 0, 0);
            a = __builtin_amdgcn_mfma_f32_16x16x32_bf16(qf0[1], kf[nt*2+1], a, 0, 0, 0);
            s0[nt] = a;
        }
        #pragma unroll
        for (int nt = 0; nt < 4; nt++) {
            f32x4 a = {0.f, 0.f, 0.f, 0.f};
            a = __builtin_amdgcn_mfma_f32_16x16x32_bf16(qf1[0], kf[nt*2+0], a, 0, 0, 0);
            a = __builtin_amdgcn_mfma_f32_16x16x32_bf16(qf1[1], kf[nt*2+1], a, 0, 0, 0);
            s1[nt] = a;
        }

        // prefetch next K fragments (kf consumed above)
        #pragma unroll
        for (int i = 0; i < 8; i++)
            kf[i] = *(const bf16x8*)(Kt + (size_t)pjt * 4096 + i * 512 + lane * 8);

        // exp2-domain softmax + ALiBi; mask only on diagonal tile (uniform);
        // both heads share identical position indices.
        const float base = slope2 * (float)(jtk * 64 + l15 - quad * 4 - qrow0);
        if (jtk == qt) {        // diagonal: apply causal mask
            #pragma unroll
            for (int nt = 0; nt < 4; nt++) {
                const int colsw = ((nt * 16 + l15) ^ wswz);
                #pragma unroll
                for (int r = 0; r < 4; r++) {
                    const float relv = (float)(jtk * 64 + l15 - quad * 4 - qrow0)
                                     + (float)(nt * 16 - r);
                    const float bb = fmaf(slope2, (float)(nt * 16 - r), base);
                    float p0 = __builtin_amdgcn_exp2f(bb + s0[nt][r]);
                    float p1 = __builtin_amdgcn_exp2f(bb + s1[nt][r]);
                    if (relv > 0.f) { p0 = 0.f; p1 = 0.f; }
                    Pw[(quad * 4 + r) * LSTR + colsw]        = f2bf_trunc(p0);
                    Pw[(16 + quad * 4 + r) * LSTR + colsw]   = f2bf_trunc(p1);
                }
            }
        } else {                // clean path
            #pragma unroll
            for (int nt = 0; nt < 4; nt++) {
                const int colsw = ((nt * 16 + l15) ^ wswz);
                #pragma unroll
                for (int r = 0; r < 4; r++) {
                    const float bb = fmaf(slope2, (float)(nt * 16 - r), base);
                    Pw[(quad * 4 + r) * LSTR + colsw] =
                        f2bf_trunc(__builtin_amdgcn_exp2f(bb + s0[nt][r]));
                    Pw[(16 + quad * 4 + r) * LSTR + colsw] =
                        f2bf_trunc(__builtin_amdgcn_exp2f(bb + s1[nt][r]));
                }
            }
        }
        __asm__ volatile("s_waitcnt lgkmcnt(0)" ::: "memory");

        // O += P @ V, l += P @ 1 for both heads (shared vf)
        {
            bf16x8 pf0 = *(const bf16x8*)&Pw[l15 * LSTR + ((quad * 8) ^ rswz)];
            bf16x8 pf1 = *(const bf16x8*)&Pw[l15 * LSTR + ((32 + quad * 8) ^ rswz)];
            lacc0 = __builtin_amdgcn_mfma_f32_16x16x32_bf16(pf0, ones, lacc0, 0, 0, 0);
            lacc0 = __builtin_amdgcn_mfma_f32_16x16x32_bf16(pf1, ones, lacc0, 0, 0, 0);
            #pragma unroll
            for (int nt = 0; nt < 4; nt++) {
                Oacc0[nt] = __builtin_amdgcn_mfma_f32_16x16x32_bf16(
                    pf0, vf[nt*2+0], Oacc0[nt], 0, 0, 0);
                Oacc0[nt] = __builtin_amdgcn_mfma_f32_16x16x32_bf16(
                    pf1, vf[nt*2+1], Oacc0[nt], 0, 0, 0);
            }
        }
        {
            bf16x8 pf0 = *(const bf16x8*)&Pw[(16 + l15) * LSTR + ((quad * 8) ^ rswz)];
            bf16x8 pf1 = *(const bf16x8*)&Pw[(16 + l15) * LSTR + ((32 + quad * 8) ^ rswz)];
            lacc1 = __builtin_amdgcn_mfma_f32_16x16x32_bf16(pf0, ones, lacc1, 0, 0, 0);
            lacc1 = __builtin_amdgcn_mfma_f32_16x16x32_bf16(pf1, ones, lacc1, 0, 0, 0);
            #pragma unroll
            for (int nt = 0; nt < 4; nt++) {
                Oacc1[nt] = __builtin_amdgcn_mfma_f32_16x16x32_bf16(
                    pf0, vf[nt*2+0], Oacc1[nt], 0, 0, 0);
                Oacc1[nt] = __builtin_amdgcn_mfma_f32_16x16x32_bf16(
                    pf1, vf[nt*2+1], Oacc1[nt], 0, 0, 0);
            }
        }

        // prefetch next V fragments (vf consumed above)
        #pragma unroll
        for (int i = 0; i < 8; i++)
            vf[i] = *(const bf16x8*)(Vt + (size_t)pjt * 4096 + i * 512 + lane * 8);
    }

    // epilogue: normalize by ones-MFMA row sums, store bf16 for both heads
    #pragma unroll
    for (int r = 0; r < 4; r++) {
        const float inv0 = 1.f / lacc0[r];
        const float inv1 = 1.f / lacc1[r];
        const int row = qrow0 + quad * 4 + r;
        short* yp = Y + (bT + row) * C_ + h0 * 64 + l15;
        #pragma unroll
        for (int nt = 0; nt < 4; nt++) {
            yp[nt * 16]      = f2bf(Oacc0[nt][r] * inv0);
            yp[64 + nt * 16] = f2bf(Oacc1[nt][r] * inv1);
        }
    }
}

extern "C" void kernel_launch(void* const* d_in, const int* in_sizes, int n_in,
                              void* d_out, int out_size, void* d_ws, size_t ws_size,
                              hipStream_t stream) {
    const float* x  = (const float*)d_in[0];
    const float* Wq = (const float*)d_in[1];
    const float* Wk = (const float*)d_in[2];
    const float* Wv = (const float*)d_in[3];
    const float* Wo = (const float*)d_in[4];
    float* out = (float*)d_out;

    const int M = B_ * T_;                           // 4096
    short* xb  = (short*)d_ws;                       // [4096][1024]
    short* Wt  = xb  + (size_t)M * C_;               // [1536][1024]
    short* Wot = Wt  + (size_t)NQKV_ * C_;           // [1024][1024]
    short* QKV = Wot + (size_t)C_ * C_;              // [4096][1536]
    short* Yb  = QKV + (size_t)M * NQKV_;            // [4096][1024]
    short* Ktg = Yb  + (size_t)M * C_;               // [8][32][4096] frag-stream
    short* Vtg = Ktg + (size_t)8 * 32 * 4096;        // [8][32][4096] frag-stream

    cast_bf16<<<dim3(M * C_ / (256 * 8)), dim3(256), 0, stream>>>(x, xb, M * C_);
    w_transpose<<<dim3(32, 32, 4), dim3(32, 8), 0, stream>>>(Wq, Wk, Wv, Wo, Wt, Wot);

    gemm_bf16<true><<<dim3(NQKV_ / 128, M / 128), dim3(256), 0, stream>>>(
        xb, Wt, QKV, M, NQKV_, C_);
    kv_tile<<<dim3(32, 8), dim3(256), 0, stream>>>(QKV, Ktg, Vtg);
    attn_mfma<<<dim3(NQT_, B_ * H_ / 2), dim3(256), 0, stream>>>(QKV, Ktg, Vtg, Yb);
    gemm_bf16<false><<<dim3(C_ / 128, M / 128), dim3(256), 0, stream>>>(
        Yb, Wot, out, M, C_, C_);
}

// Round 8
// 170.049 us; speedup vs baseline: 1.1686x; 1.0295x over previous
//
#include <hip/hip_runtime.h>
#include <hip/hip_bf16.h>
#include <math.h>

#define B_ 2
#define T_ 2048
#define C_ 1024
#define H_ 16
#define HKV_ 4
#define G_ 4
#define HD_ 64
#define KVC_ 256      // HKV*HD
#define NQKV_ 1536    // C_ + 2*KVC_
#define NQT_ 32       // T_/64 q-tiles

typedef __attribute__((ext_vector_type(8))) short bf16x8;
typedef __attribute__((ext_vector_type(4))) float f32x4;

static __device__ inline short f2bf(float f) {          // RNE (off hot path)
    __hip_bfloat16 h = __float2bfloat16(f);
    short s;
    __builtin_memcpy(&s, &h, 2);
    return s;
}
static __device__ inline short f2bf_trunc(float f) {    // RTZ, 1 op (hot path)
    unsigned int u;
    __builtin_memcpy(&u, &f, 4);
    return (short)(u >> 16);
}
static __device__ inline float bf2f(short s) {
    unsigned int u = ((unsigned int)(unsigned short)s) << 16;
    float f;
    __builtin_memcpy(&f, &u, 4);
    return f;
}

// async global->LDS, 16B per lane; lds base wave-uniform, dest = base + lane*16.
static __device__ inline void gload_lds16(const short* g, short* lds) {
    __builtin_amdgcn_global_load_lds(
        (const __attribute__((address_space(1))) unsigned int*)g,
        (__attribute__((address_space(3))) unsigned int*)lds, 16, 0, 0);
}

// ---------------- elementwise fp32 -> bf16 cast (8 elems/thread) ----------
__global__ __launch_bounds__(256) void cast_bf16(
    const float* __restrict__ in, short* __restrict__ out, int n)
{
    const int i = (blockIdx.x * 256 + threadIdx.x) * 8;
    if (i >= n) return;
    const float4 a = *(const float4*)(in + i);
    const float4 b = *(const float4*)(in + i + 4);
    bf16x8 o;
    o[0] = f2bf(a.x); o[1] = f2bf(a.y); o[2] = f2bf(a.z); o[3] = f2bf(a.w);
    o[4] = f2bf(b.x); o[5] = f2bf(b.y); o[6] = f2bf(b.z); o[7] = f2bf(b.w);
    *(bf16x8*)(out + i) = o;
}

// ------------- fused weight transpose+cast (z selects matrix) -------------
__global__ __launch_bounds__(256) void w_transpose(
    const float* __restrict__ Wq, const float* __restrict__ Wk,
    const float* __restrict__ Wv, const float* __restrict__ Wo,
    short* __restrict__ Wt, short* __restrict__ Wot)
{
    const int z = blockIdx.z;
    const float* in;
    short* out;
    int N;
    if (z == 0)      { in = Wq; out = Wt;                     N = C_; }
    else if (z == 1) { in = Wk; out = Wt + C_ * C_;           N = KVC_; }
    else if (z == 2) { in = Wv; out = Wt + (C_ + KVC_) * C_;  N = KVC_; }
    else             { in = Wo; out = Wot;                    N = C_; }
    const int n0 = blockIdx.x * 32;
    if (n0 >= N) return;
    __shared__ float t[32][33];
    const int tx = threadIdx.x, ty = threadIdx.y;     // 32 x 8
    const int k0 = blockIdx.y * 32;
    #pragma unroll
    for (int j = 0; j < 4; j++)
        t[ty + j * 8][tx] = in[(size_t)(k0 + ty + j * 8) * N + n0 + tx];
    __syncthreads();
    #pragma unroll
    for (int j = 0; j < 4; j++)
        out[(size_t)(n0 + ty + j * 8) * C_ + k0 + tx] = f2bf(t[tx][ty + j * 8]);
}

// ---------------- bf16 MFMA GEMM: 128x128 tile, BK=32, double-buffered ----
template <bool OUT_BF16>
__global__ __launch_bounds__(256) void gemm_bf16(
    const short* __restrict__ A, const short* __restrict__ Bt,
    void* __restrict__ Cout, int M, int N, int K)
{
    __shared__ short As[2][128 * 32];
    __shared__ short Bs[2][128 * 32];
    const int tid = threadIdx.x;
    const int wave = tid >> 6, lane = tid & 63;
    const int l15 = lane & 15, quad = lane >> 4;
    const int row0 = blockIdx.y * 128, col0 = blockIdx.x * 128;
    const int wr = (wave >> 1) * 64, wc = (wave & 1) * 64;
    const int sr = lane >> 2, kof = (lane & 3) * 8;

    f32x4 acc[4][4];
    #pragma unroll
    for (int i = 0; i < 4; i++)
        #pragma unroll
        for (int j = 0; j < 4; j++)
            acc[i][j] = (f32x4){0.f, 0.f, 0.f, 0.f};

#define GSTAGE(KT, BUF) do {                                                   \
        _Pragma("unroll")                                                      \
        for (int i_ = 0; i_ < 2; i_++) {                                       \
            const int rr = i_ * 64 + wave * 16;                                \
            gload_lds16(A + (size_t)(row0 + rr + sr) * K + (KT) + kof,         \
                        &As[BUF][rr * 32]);                                    \
            gload_lds16(Bt + (size_t)(col0 + rr + sr) * K + (KT) + kof,        \
                        &Bs[BUF][rr * 32]);                                    \
        }                                                                      \
    } while (0)

    GSTAGE(0, 0);
    asm volatile("s_waitcnt vmcnt(0)" ::: "memory");
    __builtin_amdgcn_s_barrier();

    int cur = 0;
    const int nkt = K >> 5;
    for (int t = 0; t < nkt; ++t) {
        if (t + 1 < nkt) GSTAGE((t + 1) * 32, cur ^ 1);

        bf16x8 af[4], bfr[4];
        #pragma unroll
        for (int mt = 0; mt < 4; mt++)
            af[mt] = *(const bf16x8*)&As[cur][(wr + mt * 16 + l15) * 32 + quad * 8];
        #pragma unroll
        for (int nt = 0; nt < 4; nt++)
            bfr[nt] = *(const bf16x8*)&Bs[cur][(wc + nt * 16 + l15) * 32 + quad * 8];
        #pragma unroll
        for (int mt = 0; mt < 4; mt++)
            #pragma unroll
            for (int nt = 0; nt < 4; nt++)
                acc[mt][nt] = __builtin_amdgcn_mfma_f32_16x16x32_bf16(
                    af[mt], bfr[nt], acc[mt][nt], 0, 0, 0);

        asm volatile("s_waitcnt vmcnt(0)" ::: "memory");
        __builtin_amdgcn_s_barrier();
        cur ^= 1;
    }
#undef GSTAGE

    #pragma unroll
    for (int mt = 0; mt < 4; mt++) {
        #pragma unroll
        for (int r = 0; r < 4; r++) {
            const size_t row = row0 + wr + mt * 16 + quad * 4 + r;
            #pragma unroll
            for (int nt = 0; nt < 4; nt++) {
                const size_t col = col0 + wc + nt * 16 + l15;
                if (OUT_BF16)
                    ((short*)Cout)[row * N + col] = f2bf(acc[mt][nt][r]);
                else
                    ((float*)Cout)[row * N + col] = acc[mt][nt][r];
            }
        }
    }
}

// ---------------- K/V tiling prepass: MFMA fragment-stream layout ---------
// Per (bk, jt) 4096-short tile, chunk i (0..7) of 512 shorts, lane = quad*16+l15:
//  K-tile chunk i=nt*2+k0, lane, j :  K[nt*16 + l15][(k0*4+quad)*8 + j]
//  V-tile chunk i=nt*2+k0, lane, j :  V^T[nt*16 + l15][k0*32 + quad*8 + j]
// so attn's kf[i]/vf[i] = one coalesced 16B/lane global load, no LDS.
__global__ __launch_bounds__(256) void kv_tile(
    const short* __restrict__ QKV, short* __restrict__ Kt, short* __restrict__ Vt)
{
    __shared__ short Ls[64 * 72];
    const int jt = blockIdx.x;         // 0..31
    const int bk = blockIdx.y;         // 0..7 = b*4+kh
    const int b = bk >> 2, kh = bk & 3;
    const int tid = threadIdx.x;
    const int key = tid >> 2, d16 = (tid & 3) * 16;
    const size_t src = (size_t)(b * T_ + jt * 64 + key) * NQKV_ + C_ + kh * 64 + d16;
    const size_t tbase = (size_t)(bk * 32 + jt) * 4096;

    {   // K: thread holds K[key][d16..d16+15] -> stream position
        const int i = (key >> 4) * 2 + (d16 >> 5);
        const int qd = (d16 & 31) >> 3;           // quad of first 8: 0 or 2
        short* dst = Kt + tbase + i * 512 + (qd * 16 + (key & 15)) * 8;
        *(bf16x8*)dst         = *(const bf16x8*)(QKV + src);      // d16..+7
        *(bf16x8*)(dst + 128) = *(const bf16x8*)(QKV + src + 8);  // d16+8..+15
    }
    // V: transpose through LDS, then stream-store
    *(bf16x8*)&Ls[key * 72 + d16]     = *(const bf16x8*)(QKV + src + KVC_);
    *(bf16x8*)&Ls[key * 72 + d16 + 8] = *(const bf16x8*)(QKV + src + KVC_ + 8);
    __syncthreads();
    const int d = tid >> 2, k16 = (tid & 3) * 16;
    bf16x8 o0, o1;
    #pragma unroll
    for (int i = 0; i < 8; i++) o0[i] = Ls[(k16 + i) * 72 + d];      // V^T[d][k16..+7]
    #pragma unroll
    for (int i = 0; i < 8; i++) o1[i] = Ls[(k16 + 8 + i) * 72 + d];  // V^T[d][k16+8..+15]
    {
        const int i = (d >> 4) * 2 + (k16 >> 5);
        const int qk = (k16 & 31) >> 3;           // 0 or 2
        short* dst = Vt + tbase + i * 512 + (qk * 16 + (d & 15)) * 8;
        *(bf16x8*)dst         = o0;
        *(bf16x8*)(dst + 128) = o1;
    }
}

// ---------------- MFMA flash attention, pipelined dual-pipe ---------------
// v8 = round-5 structure (best verified: paired q-tiles, frag-stream K/V
// global->VGPR, no main-loop barriers) + two register-only changes:
//  (1) QK[j+1] issues BETWEEN P-write[j] and P-read[j]: the register-only
//      MFMA cluster fills the LDS write->read gap, and softmax[j+1] no
//      longer trails an idle MFMA pipe (T15 dual-pipe overlap). Ping-pong
//      s-state (sA/sB), unroll-2, statically indexed.
//  (2) s_setprio(1) around MFMA clusters (m191 regime: barrier-free waves).
// __launch_bounds__(256,2): grid caps at 2 blocks/CU = 2 waves/SIMD, so
// VGPR up to 256 is occupancy-free; avoid the 128-cap spill.
#define LSTR 72

// one pipeline stage: softmax[j] from SCUR; QK[j+1] into SNXT; PV[j].
#define ATTN_ITER(J, SCURH, SCURL, SNXTH, SNXTL)                               \
  {                                                                            \
    const int j_ = (J);                                                        \
    const bool doL_ = (j_ <= qtL);                                             \
    /* softmax H from SCURH */                                                 \
    {                                                                          \
        const float base = slope2 * (float)(j_ * 64 + l15 - quad * 4 - qrow0H);\
        if (j_ == qtH) {                                                       \
            _Pragma("unroll")                                                  \
            for (int nt = 0; nt < 4; nt++) {                                   \
                const int colsw = ((nt * 16 + l15) ^ wswz);                    \
                _Pragma("unroll")                                              \
                for (int r = 0; r < 4; r++) {                                  \
                    const float relv = (float)(j_ * 64 + l15 - quad * 4 - qrow0H)\
                                     + (float)(nt * 16 - r);                   \
                    float p = __builtin_amdgcn_exp2f(                          \
                        fmaf(slope2, (float)(nt * 16 - r), base) + SCURH[nt][r]);\
                    if (relv > 0.f) p = 0.f;                                   \
                    Pw[(quad * 4 + r) * LSTR + colsw] = f2bf_trunc(p);         \
                }                                                              \
            }                                                                  \
        } else {                                                               \
            _Pragma("unroll")                                                  \
            for (int nt = 0; nt < 4; nt++) {                                   \
                const int colsw = ((nt * 16 + l15) ^ wswz);                    \
                _Pragma("unroll")                                              \
                for (int r = 0; r < 4; r++) {                                  \
                    float p = __builtin_amdgcn_exp2f(                          \
                        fmaf(slope2, (float)(nt * 16 - r), base) + SCURH[nt][r]);\
                    Pw[(quad * 4 + r) * LSTR + colsw] = f2bf_trunc(p);         \
                }                                                              \
            }                                                                  \
        }                                                                      \
    }                                                                          \
    if (doL_) {                                                                \
        const float base = slope2 * (float)(j_ * 64 + l15 - quad * 4 - qrow0L);\
        if (j_ == qtL) {                                                       \
            _Pragma("unroll")                                                  \
            for (int nt = 0; nt < 4; nt++) {                                   \
                const int colsw = ((nt * 16 + l15) ^ wswz);                    \
                _Pragma("unroll")                                              \
                for (int r = 0; r < 4; r++) {                                  \
                    const float relv = (float)(j_ * 64 + l15 - quad * 4 - qrow0L)\
                                     + (float)(nt * 16 - r);                   \
                    float p = __builtin_amdgcn_exp2f(                          \
                        fmaf(slope2, (float)(nt * 16 - r), base) + SCURL[nt][r]);\
                    if (relv > 0.f) p = 0.f;                                   \
                    Pw[(16 + quad * 4 + r) * LSTR + colsw] = f2bf_trunc(p);    \
                }                                                              \
            }                                                                  \
        } else {                                                               \
            _Pragma("unroll")                                                  \
            for (int nt = 0; nt < 4; nt++) {                                   \
                const int colsw = ((nt * 16 + l15) ^ wswz);                    \
                _Pragma("unroll")                                              \
                for (int r = 0; r < 4; r++) {                                  \
                    float p = __builtin_amdgcn_exp2f(                          \
                        fmaf(slope2, (float)(nt * 16 - r), base) + SCURL[nt][r]);\
                    Pw[(16 + quad * 4 + r) * LSTR + colsw] = f2bf_trunc(p);    \
                }                                                              \
            }                                                                  \
        }                                                                      \
    }                                                                          \
    /* QK[j+1] (register-only) fills the LDS write->read gap */                \
    if (j_ < qtH) {                                                            \
        const bool doLn_ = (j_ + 1 <= qtL);                                    \
        __builtin_amdgcn_s_setprio(1);                                         \
        _Pragma("unroll")                                                      \
        for (int nt = 0; nt < 4; nt++) {                                       \
            f32x4 a = {0.f, 0.f, 0.f, 0.f};                                    \
            a = __builtin_amdgcn_mfma_f32_16x16x32_bf16(qfH[0], kf[nt*2+0], a, 0, 0, 0);\
            a = __builtin_amdgcn_mfma_f32_16x16x32_bf16(qfH[1], kf[nt*2+1], a, 0, 0, 0);\
            SNXTH[nt] = a;                                                     \
        }                                                                      \
        if (doLn_) {                                                           \
            _Pragma("unroll")                                                  \
            for (int nt = 0; nt < 4; nt++) {                                   \
                f32x4 a = {0.f, 0.f, 0.f, 0.f};                                \
                a = __builtin_amdgcn_mfma_f32_16x16x32_bf16(qfL[0], kf[nt*2+0], a, 0, 0, 0);\
                a = __builtin_amdgcn_mfma_f32_16x16x32_bf16(qfL[1], kf[nt*2+1], a, 0, 0, 0);\
                SNXTL[nt] = a;                                                 \
            }                                                                  \
        }                                                                      \
        __builtin_amdgcn_s_setprio(0);                                         \
        const int pk_ = (j_ + 2 <= qtH) ? j_ + 2 : qtH;                        \
        _Pragma("unroll")                                                      \
        for (int i = 0; i < 8; i++)                                            \
            kf[i] = *(const bf16x8*)(Kt + (size_t)pk_ * 4096 + i * 512 + lane * 8);\
    }                                                                          \
    __asm__ volatile("s_waitcnt lgkmcnt(0)" ::: "memory");                     \
    /* PV[j]: O += P @ V, l += P @ 1 */                                        \
    {                                                                          \
        bf16x8 pf0 = *(const bf16x8*)&Pw[l15 * LSTR + ((quad * 8) ^ rswz)];    \
        bf16x8 pf1 = *(const bf16x8*)&Pw[l15 * LSTR + ((32 + quad * 8) ^ rswz)];\
        __builtin_amdgcn_s_setprio(1);                                         \
        laccH = __builtin_amdgcn_mfma_f32_16x16x32_bf16(pf0, ones, laccH, 0, 0, 0);\
        laccH = __builtin_amdgcn_mfma_f32_16x16x32_bf16(pf1, ones, laccH, 0, 0, 0);\
        _Pragma("unroll")                                                      \
        for (int nt = 0; nt < 4; nt++) {                                       \
            OaccH[nt] = __builtin_amdgcn_mfma_f32_16x16x32_bf16(               \
                pf0, vf[nt*2+0], OaccH[nt], 0, 0, 0);                          \
            OaccH[nt] = __builtin_amdgcn_mfma_f32_16x16x32_bf16(               \
                pf1, vf[nt*2+1], OaccH[nt], 0, 0, 0);                          \
        }                                                                      \
        __builtin_amdgcn_s_setprio(0);                                         \
    }                                                                          \
    if (doL_) {                                                                \
        bf16x8 pf0 = *(const bf16x8*)&Pw[(16 + l15) * LSTR + ((quad * 8) ^ rswz)];\
        bf16x8 pf1 = *(const bf16x8*)&Pw[(16 + l15) * LSTR + ((32 + quad * 8) ^ rswz)];\
        __builtin_amdgcn_s_setprio(1);                                         \
        laccL = __builtin_amdgcn_mfma_f32_16x16x32_bf16(pf0, ones, laccL, 0, 0, 0);\
        laccL = __builtin_amdgcn_mfma_f32_16x16x32_bf16(pf1, ones, laccL, 0, 0, 0);\
        _Pragma("unroll")                                                      \
        for (int nt = 0; nt < 4; nt++) {                                       \
            OaccL[nt] = __builtin_amdgcn_mfma_f32_16x16x32_bf16(               \
                pf0, vf[nt*2+0], OaccL[nt], 0, 0, 0);                          \
            OaccL[nt] = __builtin_amdgcn_mfma_f32_16x16x32_bf16(               \
                pf1, vf[nt*2+1], OaccL[nt], 0, 0, 0);                          \
        }                                                                      \
        __builtin_amdgcn_s_setprio(0);                                         \
    }                                                                          \
    const int pv_ = (j_ + 1 <= qtH) ? j_ + 1 : qtH;                            \
    _Pragma("unroll")                                                          \
    for (int i = 0; i < 8; i++)                                                \
        vf[i] = *(const bf16x8*)(Vt + (size_t)pv_ * 4096 + i * 512 + lane * 8);\
  }

__global__ __launch_bounds__(256, 2) void attn_mfma(
    const short* __restrict__ QKV, const short* __restrict__ Ktg,
    const short* __restrict__ Vtg, short* __restrict__ Y)
{
    const int qx = blockIdx.x;                 // 0..15
    const int bh = blockIdx.y;
    const int qtL = qx, qtH = NQT_ - 1 - qx;   // pair sums to 31
    const int b = bh >> 4, h = bh & 15, kh = h >> 2;
    const float slope2 = exp2f(-0.5f * (float)(kh + 1)) * 1.44269504f;
    const int tid = threadIdx.x;
    const int wave = tid >> 6, lane = tid & 63;
    const int l15 = lane & 15, quad = lane >> 4;

    __shared__ short Ps[4 * 32 * LSTR];        // per wave: rows 0-15 H, 16-31 L
    short* Pw = &Ps[wave * 32 * LSTR];
    const int wswz = ((quad >> 1) & 1) << 4;   // P write XOR (row bit3)
    const int rswz = ((l15 >> 3) & 1) << 4;    // P read  XOR (row bit3)

    const size_t bT = (size_t)b * T_;
    const size_t tb0 = (size_t)((b * HKV_ + kh) * 32) * 4096;
    const short* Kt = Ktg + tb0;
    const short* Vt = Vtg + tb0;
    const int qrow0H = qtH * 64 + wave * 16;
    const int qrow0L = qtL * 64 + wave * 16;

    // Q fragments; scale 1/8 * 1/ln2 folded in (exp2-domain scores)
    const float qscale = 0.125f * 1.44269504f;
    bf16x8 qfH[2], qfL[2];
    #pragma unroll
    for (int k0 = 0; k0 < 2; k0++) {
        const short* qpH = QKV + (bT + qrow0H + l15) * NQKV_ + h * 64;
        const short* qpL = QKV + (bT + qrow0L + l15) * NQKV_ + h * 64;
        bf16x8 rH = *(const bf16x8*)(qpH + k0 * 32 + quad * 8);
        bf16x8 rL = *(const bf16x8*)(qpL + k0 * 32 + quad * 8);
        #pragma unroll
        for (int j = 0; j < 8; j++) {
            qfH[k0][j] = f2bf(bf2f(rH[j]) * qscale);
            qfL[k0][j] = f2bf(bf2f(rL[j]) * qscale);
        }
    }

    const short one_s = (short)0x3F80;         // bf16 1.0
    const bf16x8 ones = {one_s, one_s, one_s, one_s, one_s, one_s, one_s, one_s};

    f32x4 OaccH[4], OaccL[4], laccH, laccL;
    #pragma unroll
    for (int nt = 0; nt < 4; nt++) {
        OaccH[nt] = (f32x4){0.f, 0.f, 0.f, 0.f};
        OaccL[nt] = (f32x4){0.f, 0.f, 0.f, 0.f};
    }
    laccH = (f32x4){0.f, 0.f, 0.f, 0.f};
    laccL = (f32x4){0.f, 0.f, 0.f, 0.f};

    // prologue: K/V tile-0 fragments, then QK[0] into the A s-state
    bf16x8 kf[8], vf[8];
    #pragma unroll
    for (int i = 0; i < 8; i++)
        kf[i] = *(const bf16x8*)(Kt + i * 512 + lane * 8);
    #pragma unroll
    for (int i = 0; i < 8; i++)
        vf[i] = *(const bf16x8*)(Vt + i * 512 + lane * 8);

    f32x4 sAH[4], sAL[4], sBH[4], sBL[4];
    #pragma unroll
    for (int nt = 0; nt < 4; nt++) {
        f32x4 a = {0.f, 0.f, 0.f, 0.f};
        a = __builtin_amdgcn_mfma_f32_16x16x32_bf16(qfH[0], kf[nt*2+0], a, 0, 0, 0);
        a = __builtin_amdgcn_mfma_f32_16x16x32_bf16(qfH[1], kf[nt*2+1], a, 0, 0, 0);
        sAH[nt] = a;
    }
    #pragma unroll
    for (int nt = 0; nt < 4; nt++) {           // doL(0) is always true
        f32x4 a = {0.f, 0.f, 0.f, 0.f};
        a = __builtin_amdgcn_mfma_f32_16x16x32_bf16(qfL[0], kf[nt*2+0], a, 0, 0, 0);
        a = __builtin_amdgcn_mfma_f32_16x16x32_bf16(qfL[1], kf[nt*2+1], a, 0, 0, 0);
        sAL[nt] = a;
    }
    {   // prefetch K tile 1 (qtH >= 16, so tile 1 always exists)
        #pragma unroll
        for (int i = 0; i < 8; i++)
            kf[i] = *(const bf16x8*)(Kt + (size_t)4096 + i * 512 + lane * 8);
    }

    for (int j = 0; j <= qtH; j += 2) {
        ATTN_ITER(j, sAH, sAL, sBH, sBL);
        if (j + 1 <= qtH)
            ATTN_ITER(j + 1, sBH, sBL, sAH, sAL);
    }

    // epilogue: l = lacc[r] (same in all 16 col-lanes), normalize, store bf16
    #pragma unroll
    for (int r = 0; r < 4; r++) {
        const float invH = 1.f / laccH[r];
        const float invL = 1.f / laccL[r];
        const int rowH = qrow0H + quad * 4 + r;
        const int rowL = qrow0L + quad * 4 + r;
        short* ypH = Y + (bT + rowH) * C_ + h * 64 + l15;
        short* ypL = Y + (bT + rowL) * C_ + h * 64 + l15;
        #pragma unroll
        for (int nt = 0; nt < 4; nt++) {
            ypH[nt * 16] = f2bf(OaccH[nt][r] * invH);
            ypL[nt * 16] = f2bf(OaccL[nt][r] * invL);
        }
    }
}

extern "C" void kernel_launch(void* const* d_in, const int* in_sizes, int n_in,
                              void* d_out, int out_size, void* d_ws, size_t ws_size,
                              hipStream_t stream) {
    const float* x  = (const float*)d_in[0];
    const float* Wq = (const float*)d_in[1];
    const float* Wk = (const float*)d_in[2];
    const float* Wv = (const float*)d_in[3];
    const float* Wo = (const float*)d_in[4];
    float* out = (float*)d_out;

    const int M = B_ * T_;                           // 4096
    short* xb  = (short*)d_ws;                       // [4096][1024]
    short* Wt  = xb  + (size_t)M * C_;               // [1536][1024]
    short* Wot = Wt  + (size_t)NQKV_ * C_;           // [1024][1024]
    short* QKV = Wot + (size_t)C_ * C_;              // [4096][1536]
    short* Yb  = QKV + (size_t)M * NQKV_;            // [4096][1024]
    short* Ktg = Yb  + (size_t)M * C_;               // [8][32][4096] frag-stream
    short* Vtg = Ktg + (size_t)8 * 32 * 4096;        // [8][32][4096] frag-stream

    cast_bf16<<<dim3(M * C_ / (256 * 8)), dim3(256), 0, stream>>>(x, xb, M * C_);
    w_transpose<<<dim3(32, 32, 4), dim3(32, 8), 0, stream>>>(Wq, Wk, Wv, Wo, Wt, Wot);

    gemm_bf16<true><<<dim3(NQKV_ / 128, M / 128), dim3(256), 0, stream>>>(
        xb, Wt, QKV, M, NQKV_, C_);
    kv_tile<<<dim3(32, 8), dim3(256), 0, stream>>>(QKV, Ktg, Vtg);
    attn_mfma<<<dim3(NQT_ / 2, B_ * H_), dim3(256), 0, stream>>>(QKV, Ktg, Vtg, Yb);
    gemm_bf16<false><<<dim3(C_ / 128, M / 128), dim3(256), 0, stream>>>(
        Yb, Wot, out, M, C_, C_);
}